// Round 15
// baseline (519.903 us; speedup 1.0000x reference)
//
#include <hip/hip_runtime.h>
#include <hip/hip_bf16.h>
#include <hip/hip_cooperative_groups.h>
#include <stdint.h>

namespace cg = cooperative_groups;

// BertAttention (feature-axis attention), algebraically restructured:
//   G = x^T x (SYMMETRIC -> 10/16 tile-pairs); m = colsum(x)
//   u2 = Wq m + S*bq;  w = Wk m
//   scores = (Wq G Wk^T + u2 bk^T + bq w^T)/sqrt(D); attn = softmax(scores)
//   out = x (Wv^T attn) + 1 (bv^T attn)
// 5 launches: zero, cast_transpose, g_and_prep (G-GEMM + weight prep),
// midchain (cooperative: reduceG+mirror / U / reduceU / scores / softmax /
// MT / reduceMT+bv with grid.sync), gemm128 (out).

#define S_ 16384
#define D_ 1024

typedef _Float16 half8 __attribute__((ext_vector_type(8)));
typedef _Float16 half4 __attribute__((ext_vector_type(4)));
typedef float f32x4 __attribute__((ext_vector_type(4)));

__device__ __forceinline__ void gload_lds16(const _Float16* g, _Float16* l) {
    __builtin_amdgcn_global_load_lds(
        (const __attribute__((address_space(1))) void*)g,
        (__attribute__((address_space(3))) void*)l, 16, 0, 0);
}

#define VM8() do { asm volatile("s_waitcnt vmcnt(8)" ::: "memory"); __builtin_amdgcn_sched_barrier(0); } while (0)
#define VM0() do { asm volatile("s_waitcnt vmcnt(0)" ::: "memory"); __builtin_amdgcn_sched_barrier(0); } while (0)
#define BAR() __builtin_amdgcn_s_barrier()
#define LGKM0() do { asm volatile("s_waitcnt lgkmcnt(0)" ::: "memory"); __builtin_amdgcn_sched_barrier(0); } while (0)
#define LGKM8() do { asm volatile("s_waitcnt lgkmcnt(8)" ::: "memory"); __builtin_amdgcn_sched_barrier(0); } while (0)
#define PRIO1() __builtin_amdgcn_s_setprio(1)
#define PRIO0() __builtin_amdgcn_s_setprio(0)

#define PAIR10(PI, BY, BX) do { \
    if ((PI) < 4) { BY = 0; BX = (PI); } \
    else if ((PI) < 7) { BY = 1; BX = (PI) - 3; } \
    else if ((PI) < 9) { BY = 2; BX = (PI) - 5; } \
    else { BY = 3; BX = 3; } \
} while (0)

// ========== g_and_prep: blocks [0,160) = G-GEMM (256^2 engine, upper
// triangle, z=16, f16 partials); blocks [160,800) = weight prep.
#define STAGEA(H, KT, NX) do { \
    const _Float16* _s = srcA + (size_t)((H) * 128) * 16384 + (size_t)(KT) * 64; \
    _Float16* _d = AsS + (NX) * 16384 + ((H) * 128 + 8 * w) * 64; \
    gload_lds16(_s, _d); \
    gload_lds16(_s + (size_t)64 * 16384, _d + 4096); \
} while (0)

#define STAGEB(H, KT, NX) do { \
    const _Float16* _s = srcB + (size_t)((H) * 128) * 16384 + (size_t)(KT) * 64; \
    _Float16* _d = BsS + (NX) * 16384 + ((H) * 128 + 8 * w) * 64; \
    gload_lds16(_s, _d); \
    gload_lds16(_s + (size_t)64 * 16384, _d + 4096); \
} while (0)

#define READA(PA, QA) do { _Pragma("unroll") \
    for (int fm = 0; fm < 4; ++fm) { \
        af[fm][0] = *(const half8*)((PA) + (((QA) * 128 + fm * 16) << 7) + cx0); \
        af[fm][1] = *(const half8*)((PA) + (((QA) * 128 + fm * 16) << 7) + cx1); } \
} while (0)

#define READB(PB, BF, QB) do { _Pragma("unroll") \
    for (int fn = 0; fn < 2; ++fn) { \
        BF[fn][0] = *(const half8*)((PB) + (((QB) * 128 + fn * 16) << 7) + cx0); \
        BF[fn][1] = *(const half8*)((PB) + (((QB) * 128 + fn * 16) << 7) + cx1); } \
} while (0)

#define MFMAB(QA, QB, BF) do { _Pragma("unroll") \
    for (int fm = 0; fm < 4; ++fm) { _Pragma("unroll") \
        for (int fn = 0; fn < 2; ++fn) { \
            f32x4 _c = acc[(QA) * 4 + fm][(QB) * 2 + fn]; \
            _c = __builtin_amdgcn_mfma_f32_16x16x32_f16(af[fm][0], BF[fn][0], _c, 0, 0, 0); \
            _c = __builtin_amdgcn_mfma_f32_16x16x32_f16(af[fm][1], BF[fn][1], _c, 0, 0, 0); \
            acc[(QA) * 4 + fm][(QB) * 2 + fn] = _c; } } \
} while (0)

__global__ __launch_bounds__(512, 2)
void g_and_prep(const _Float16* __restrict__ A, _Float16* __restrict__ C,
                const float* __restrict__ Wq, const float* __restrict__ Wk,
                const float* __restrict__ Wv, const float* __restrict__ bq,
                const float* __restrict__ m,
                _Float16* __restrict__ wq16, _Float16* __restrict__ wk16,
                _Float16* __restrict__ wvT16,
                float* __restrict__ u2, float* __restrict__ wvec) {
    __shared__ _Float16 SM2[65536];   // 128KB
    const int t = threadIdx.x;

    if (blockIdx.x < 160) {
        _Float16* AsS = SM2;
        _Float16* BsS = SM2 + 32768;
        const int l = t & 63;
        const int w = t >> 6;
        const int wm = w >> 2, wn = w & 3;

        const int hb = blockIdx.x;
        const int lg = (hb & 7) * 20 + (hb >> 3);
        const int bz = lg / 10;
        const int pi = lg - bz * 10;
        int by, bx;
        PAIR10(pi, by, bx);
        const size_t m0 = (size_t)by * 256;
        const size_t n0 = (size_t)bx * 256;
        const size_t k0 = (size_t)bz * 1024;
        const long long coff = (long long)bz * 1048576LL;

        const int colsw = 8 * ((l & 7) ^ (l >> 3));
        const _Float16* srcA = A + (m0 + 8 * w + (l >> 3)) * (size_t)16384 + k0 + colsw;
        const _Float16* srcB = A + (n0 + 8 * w + (l >> 3)) * (size_t)16384 + k0 + colsw;

        const int cx0 = (((l >> 4) << 4)) ^ ((l & 7) << 4);
        const int cx1 = (64 + ((l >> 4) << 4)) ^ ((l & 7) << 4);
        const char* basePA = (const char*)AsS + ((wm * 64 + (l & 15)) << 7);
        const char* basePB = (const char*)BsS + ((wn * 32 + (l & 15)) << 7);

        f32x4 acc[8][4] = {};
        half8 af[4][2], bf0[2][2], bf1[2][2];

        const int nk = 16;

        STAGEA(0, 0, 0); STAGEB(0, 0, 0); STAGEB(1, 0, 0); STAGEA(1, 0, 0);
        STAGEA(0, 1, 1); STAGEB(0, 1, 1); STAGEB(1, 1, 1); STAGEA(1, 1, 1);

        for (int kt = 0; kt < nk; ++kt) {
            const int p = kt & 1;
            const int ks = kt + 2;
            const bool hs = ks < nk;
            const char* pA = basePA + p * 32768;
            const char* pB = basePB + p * 32768;

            if (kt == nk - 1) VM0(); else VM8();
            BAR();

            READA(pA, 0); READB(pB, bf0, 0);
            LGKM8();
            BAR(); LGKM0();
            PRIO1(); MFMAB(0, 0, bf0); PRIO0(); BAR();

            READB(pB, bf1, 1);
            if (hs) { STAGEA(0, ks, p); STAGEB(0, ks, p); }
            BAR(); LGKM0();
            PRIO1(); MFMAB(0, 1, bf1); PRIO0(); BAR();

            READA(pA, 1);
            if (hs) STAGEB(1, ks, p);
            BAR(); LGKM0();
            PRIO1(); MFMAB(1, 1, bf1); PRIO0(); BAR();

            if (hs) STAGEA(1, ks, p);
            PRIO1(); MFMAB(1, 0, bf0); PRIO0(); BAR();
        }

        _Float16* eb = SM2;
        const int cr = (l >> 4) << 2;
        const int cc = l & 15;
#pragma unroll
        for (int h = 0; h < 2; ++h) {
            BAR();
#pragma unroll
            for (int mm = 0; mm < 4; ++mm) {
#pragma unroll
                for (int n = 0; n < 4; ++n) {
                    const int lrow0 = wm * 64 + mm * 16 + cr;
                    const int lcol = (n >> 1) * 128 + wn * 32 + (n & 1) * 16 + cc;
#pragma unroll
                    for (int r = 0; r < 4; ++r)
                        eb[(lrow0 + r) * 264 + lcol] = (_Float16)acc[h * 4 + mm][n][r];
                }
            }
            LGKM0();
            BAR();
#pragma unroll
            for (int i = 0; i < 8; ++i) {
                const int lrow = w * 16 + i * 2 + (l >> 5);
                const half8 v = *(const half8*)(eb + lrow * 264 + (l & 31) * 8);
                const size_t row = m0 + (size_t)h * 128 + lrow;
                const size_t col = n0 + (l & 31) * 8;
                __builtin_nontemporal_store(v,
                    (half8*)(C + coff + (long long)row * 1024 + col));
            }
            LGKM0();
        }
        return;
    }

    // prep path (two virtual 256-thread blocks)
    const int h = t >> 8;
    const int vt = t & 255;
    const int vb = (blockIdx.x - 160) * 2 + h;
    _Float16* tileh = SM2 + h * 4224;
    float* wredAll = (float*)(SM2 + 16896);
    const bool isW = vb < 1024;

    if (isW) {
        const bool isQ = vb < 512;
        const int bb = isQ ? vb : vb - 512;
        const float* W = isQ ? Wq : Wk;
        _Float16* o = isQ ? wq16 : wk16;
        const size_t base = (size_t)bb * 2048 + (size_t)vt * 8;
        const f32x4* p = (const f32x4*)(W + base);
        f32x4 x0 = p[0], x1 = p[1];
        half8 hv;
        hv[0] = (_Float16)x0[0]; hv[1] = (_Float16)x0[1];
        hv[2] = (_Float16)x0[2]; hv[3] = (_Float16)x0[3];
        hv[4] = (_Float16)x1[0]; hv[5] = (_Float16)x1[1];
        hv[6] = (_Float16)x1[2]; hv[7] = (_Float16)x1[3];
        ((half8*)o)[bb * 256 + vt] = hv;
        const int col = (vt * 8) & 1023;
        f32x4 m0v = *(const f32x4*)(m + col);
        f32x4 m1v = *(const f32x4*)(m + col + 4);
        float s = x0[0] * m0v[0] + x0[1] * m0v[1] + x0[2] * m0v[2] + x0[3] * m0v[3]
                + x1[0] * m1v[0] + x1[1] * m1v[1] + x1[2] * m1v[2] + x1[3] * m1v[3];
        for (int o2 = 32; o2; o2 >>= 1) s += __shfl_xor(s, o2);
        if ((t & 63) == 0) wredAll[t >> 6] = s;
    } else {
        const int bb = vb - 1024;
        const int c0 = (bb & 15) * 64;
        const int r0 = (bb >> 4) * 64;
        const int cg = vt & 15;
        const int rb = vt >> 4;
#pragma unroll
        for (int it = 0; it < 4; ++it) {
            const int rr = rb + it * 16;
            f32x4 v = *(const f32x4*)(Wv + (size_t)(r0 + rr) * 1024 + c0 + cg * 4);
            tileh[rr * 66 + cg * 4 + 0] = (_Float16)v[0];
            tileh[rr * 66 + cg * 4 + 1] = (_Float16)v[1];
            tileh[rr * 66 + cg * 4 + 2] = (_Float16)v[2];
            tileh[rr * 66 + cg * 4 + 3] = (_Float16)v[3];
        }
    }
    __syncthreads();
    if (isW) {
        if (vt == 0) {
            const bool isQ = vb < 512;
            const int bb = isQ ? vb : vb - 512;
            const int rA = 2 * bb, rB = 2 * bb + 1;
            const float vA = wredAll[h * 4 + 0] + wredAll[h * 4 + 1];
            const float vB = wredAll[h * 4 + 2] + wredAll[h * 4 + 3];
            if (isQ) {
                u2[rA] = vA + 16384.0f * bq[rA];
                u2[rB] = vB + 16384.0f * bq[rB];
            } else {
                wvec[rA] = vA;
                wvec[rB] = vB;
            }
        }
    } else {
        const int bb = vb - 1024;
        const int c0 = (bb & 15) * 64;
        const int r0 = (bb >> 4) * 64;
        const int i = vt >> 2, ch = (vt & 3) * 16;
        half8 h0v, h1v;
#pragma unroll
        for (int j = 0; j < 8; ++j) h0v[j] = tileh[(ch + j) * 66 + i];
#pragma unroll
        for (int j = 0; j < 8; ++j) h1v[j] = tileh[(ch + 8 + j) * 66 + i];
        *(half8*)(wvT16 + (size_t)(c0 + i) * 1024 + r0 + ch) = h0v;
        *(half8*)(wvT16 + (size_t)(c0 + i) * 1024 + r0 + ch + 8) = h1v;
    }
}

// ================= midchain device bodies (validated round-14 code) =======
__device__ __forceinline__ void stg128f(const _Float16* src, _Float16* dst,
                                        int kt, int w) {
    const _Float16* s = src + (size_t)kt * 64;
    _Float16* d = dst + 8 * w * 64;
    gload_lds16(s, d);
    gload_lds16(s + 32 * 1024, d + 2048);
    gload_lds16(s + 64 * 1024, d + 4096);
    gload_lds16(s + 96 * 1024, d + 6144);
}

// 128^2 split-K GEMM body (1024x1024, ksub=256, z=idx>>6). f16out: f16
// partials via cooperative restage; else fp32 partials per-wave restage.
__device__ __forceinline__ void gemm_body(const _Float16* __restrict__ A,
                                          const _Float16* __restrict__ B,
                                          void* __restrict__ C, int f16out,
                                          _Float16* SM, int idx) {
    const int t = threadIdx.x;
    const int l = t & 63;
    const int w = t >> 6;
    const int wm = w >> 1, wn = w & 1;
    const int bx = idx & 7, by = (idx >> 3) & 7, bz = idx >> 6;
    const size_t m0 = (size_t)by * 128;
    const size_t n0 = (size_t)bx * 128;
    const size_t k0 = (size_t)bz * 256;
    const long long coff = (long long)bz * 1048576LL;

    const int colsw = 8 * ((l & 7) ^ (l >> 3));
    const _Float16* srcA = A + (m0 + 8 * w + (l >> 3)) * (size_t)1024 + k0 + colsw;
    const _Float16* srcB = B + (n0 + 8 * w + (l >> 3)) * (size_t)1024 + k0 + colsw;

    const int cx0 = (((l >> 4) << 4)) ^ ((l & 7) << 4);
    const int cx1 = (64 + ((l >> 4) << 4)) ^ ((l & 7) << 4);
    const char* basePA = (const char*)SM + ((wm * 64 + (l & 15)) << 7);
    const char* basePB = (const char*)SM + 32768 + ((wn * 64 + (l & 15)) << 7);

    f32x4 acc[4][4] = {};
    half8 af[4][2], bf[4][2];
    const int nk = 4;

    stg128f(srcA, SM + 0, 0, w);      stg128f(srcB, SM + 16384, 0, w);
    stg128f(srcA, SM + 8192, 1, w);   stg128f(srcB, SM + 24576, 1, w);

    for (int kt = 0; kt < nk; ++kt) {
        const int p = kt & 1;
        const int ks = kt + 2;
        const bool hs = ks < nk;
        const char* pA = basePA + p * 16384;
        const char* pB = basePB + p * 16384;

        if (kt == nk - 1) VM0(); else VM8();
        BAR();

#pragma unroll
        for (int fm = 0; fm < 4; ++fm) {
            af[fm][0] = *(const half8*)(pA + ((fm * 16) << 7) + cx0);
            af[fm][1] = *(const half8*)(pA + ((fm * 16) << 7) + cx1);
        }
#pragma unroll
        for (int fn = 0; fn < 4; ++fn) {
            bf[fn][0] = *(const half8*)(pB + ((fn * 16) << 7) + cx0);
            bf[fn][1] = *(const half8*)(pB + ((fn * 16) << 7) + cx1);
        }
        LGKM0();
        PRIO1();
#pragma unroll
        for (int fm = 0; fm < 4; ++fm)
#pragma unroll
            for (int fn = 0; fn < 4; ++fn)
                acc[fm][fn] = __builtin_amdgcn_mfma_f32_16x16x32_f16(af[fm][0], bf[fn][0], acc[fm][fn], 0, 0, 0);
        PRIO0();
        BAR();

        if (hs) {
            stg128f(srcA, SM + p * 8192, ks, w);
            stg128f(srcB, SM + 16384 + p * 8192, ks, w);
        }
        PRIO1();
#pragma unroll
        for (int fm = 0; fm < 4; ++fm)
#pragma unroll
            for (int fn = 0; fn < 4; ++fn)
                acc[fm][fn] = __builtin_amdgcn_mfma_f32_16x16x32_f16(af[fm][1], bf[fn][1], acc[fm][fn], 0, 0, 0);
        PRIO0();
        BAR();
    }

    const int cr = (l >> 4) << 2;
    const int cc = l & 15;

    if (f16out) {
        _Float16* eb = SM;
#pragma unroll
        for (int fm = 0; fm < 4; ++fm) {
#pragma unroll
            for (int fn = 0; fn < 4; ++fn) {
                const int lrow0 = wm * 64 + fm * 16 + cr;
                const int lcol = wn * 64 + fn * 16 + cc;
#pragma unroll
                for (int r = 0; r < 4; ++r)
                    eb[(lrow0 + r) * 132 + lcol] = (_Float16)acc[fm][fn][r];
            }
        }
        LGKM0();
        BAR();
        _Float16* Ch = (_Float16*)C;
#pragma unroll
        for (int i = 0; i < 8; ++i) {
            const int row = i * 16 + (t >> 4);
            const int colh = (t & 15) * 8;
            const half8 v = *(const half8*)(eb + row * 132 + colh);
            *(half8*)(Ch + coff + (long long)(m0 + row) * 1024 + n0 + colh) = v;
        }
    } else {
        float* lw = (float*)((char*)SM + w * 16384);
        float* Cf = (float*)C;
#pragma unroll
        for (int h = 0; h < 2; ++h) {
#pragma unroll
            for (int mm2 = 0; mm2 < 2; ++mm2) {
                const int mm = h * 2 + mm2;
#pragma unroll
                for (int fn = 0; fn < 4; ++fn) {
                    const int lcol = fn * 16 + cc;
                    const int lrow = mm2 * 16 + cr;
#pragma unroll
                    for (int r = 0; r < 4; ++r)
                        lw[(lrow + r) * 68 + lcol] = acc[mm][fn][r];
                }
            }
            LGKM0();
            const size_t grow0 = m0 + (size_t)wm * 64 + h * 32;
#pragma unroll
            for (int i = 0; i < 8; ++i) {
                const int lrow = i * 4 + (l >> 4);
                const int lcol = (l & 15) * 4;
                const f32x4 v = *(const f32x4*)(lw + lrow * 68 + lcol);
                *(f32x4*)(Cf + coff + (long long)(grow0 + lrow) * 1024 + n0 + wn * 64 + lcol) = v;
            }
            LGKM0();
        }
    }
    VM0();   // clean vmcnt ledger for next phase
}

// reduce 16 f16 G z-slices over an upper-triangle chunk + fused mirror.
__device__ __forceinline__ void reduce_hu_body(const _Float16* part,
                                               _Float16* G16, _Float16* lt,
                                               int b) {
    const int ti = b >> 5;
    int by, bx;
    PAIR10(ti, by, bx);
    const int t = threadIdx.x;
    const int e0 = (b & 31) * 2048 + t * 8;
    const size_t row = (size_t)by * 256 + (e0 >> 8);
    const size_t col = (size_t)bx * 256 + (e0 & 255);
    const size_t off = row * 1024 + col;
    float s[8] = {};
    for (int z = 0; z < 16; ++z) {
        half8 v = *(const half8*)(part + (size_t)z * 1048576 + off);
#pragma unroll
        for (int j = 0; j < 8; ++j) s[j] += (float)v[j];
    }
    half8 o;
#pragma unroll
    for (int j = 0; j < 8; ++j) o[j] = (_Float16)s[j];
    *(half8*)(G16 + off) = o;

    const bool offd = (by != bx);
    if (offd) {
        const int cl = (t & 31) * 8;
        const int rl = t >> 5;
#pragma unroll
        for (int j = 0; j < 8; ++j) lt[(cl + j) * 9 + rl] = o[j];
    }
    __syncthreads();
    if (offd) {
        half8 v = *(const half8*)(lt + t * 9);
        *(half8*)(G16 + ((size_t)(bx * 256 + t)) * 1024 + by * 256 + (b & 31) * 8) = v;
    }
    __syncthreads();
}

__device__ __forceinline__ void reduce_body(const _Float16* part,
                                            _Float16* outh, int vb) {
    const size_t off = ((size_t)vb * 256 + threadIdx.x) * 8;
    float s[8] = {};
    for (int z = 0; z < 4; ++z) {
        half8 v = *(const half8*)(part + (size_t)z * 1048576 + off);
#pragma unroll
        for (int j = 0; j < 8; ++j) s[j] += (float)v[j];
    }
    half8 o;
#pragma unroll
    for (int j = 0; j < 8; ++j) o[j] = (_Float16)s[j];
    *(half8*)(outh + off) = o;
}

__device__ __forceinline__ void softmax_body(const float* partF, const float* u2,
        const float* bq, const float* bk, const float* wvec,
        float* P, _Float16* PT, int a, float* red) {
    const int t = threadIdx.x;
    const size_t off = (size_t)a * 1024 + t * 4;
    f32x4 s = {};
#pragma unroll
    for (int z = 0; z < 4; ++z) {
        f32x4 v = *(const f32x4*)(partF + (size_t)z * 1048576 + off);
        s[0] += v[0]; s[1] += v[1]; s[2] += v[2]; s[3] += v[3];
    }
    const float ru = u2[a], rb = bq[a];
    f32x4 bk4 = *(const f32x4*)(bk + t * 4);
    f32x4 w4 = *(const f32x4*)(wvec + t * 4);
#pragma unroll
    for (int j = 0; j < 4; ++j) s[j] = (s[j] + ru * bk4[j] + rb * w4[j]) * 0.03125f;

    float m = fmaxf(fmaxf(s[0], s[1]), fmaxf(s[2], s[3]));
    for (int o = 32; o; o >>= 1) m = fmaxf(m, __shfl_xor(m, o));
    if ((t & 63) == 0) red[t >> 6] = m;
    __syncthreads();
    m = fmaxf(fmaxf(red[0], red[1]), fmaxf(red[2], red[3]));

    float e0 = expf(s[0] - m), e1 = expf(s[1] - m);
    float e2 = expf(s[2] - m), e3 = expf(s[3] - m);
    float sum = e0 + e1 + e2 + e3;
    for (int o = 32; o; o >>= 1) sum += __shfl_xor(sum, o);
    if ((t & 63) == 0) red[4 + (t >> 6)] = sum;
    __syncthreads();
    sum = red[4] + red[5] + red[6] + red[7];
    const float inv = 1.0f / sum;

    f32x4 o4 = {e0 * inv, e1 * inv, e2 * inv, e3 * inv};
    *(f32x4*)(P + off) = o4;
    const int b = t * 4;
    PT[(size_t)(b + 0) * 1024 + a] = (_Float16)o4[0];
    PT[(size_t)(b + 1) * 1024 + a] = (_Float16)o4[1];
    PT[(size_t)(b + 2) * 1024 + a] = (_Float16)o4[2];
    PT[(size_t)(b + 3) * 1024 + a] = (_Float16)o4[3];
    __syncthreads();
}

__device__ __forceinline__ void bv_body(const float* attn, const float* bv,
                                        float* cvec, int bb) {
    const int j = (bb & 3) * 256 + threadIdx.x;
    const int a0 = (bb >> 2) * 64;
    float s = 0.f;
#pragma unroll 4
    for (int k = 0; k < 64; ++k) {
        const int a = a0 + k;
        s += attn[(size_t)a * 1024 + j] * bv[a];
    }
    atomicAdd(cvec + j, s);
}

// =============== midchain: cooperative kernel, 256 blocks x 256 ===========
__global__ __launch_bounds__(256, 2)
void midchain(const _Float16* gpart, _Float16* G16,
              const _Float16* wq16, const _Float16* wk16,
              const _Float16* wvT16,
              _Float16* partH, float* partF,
              _Float16* U16, _Float16* MT16, _Float16* PT,
              const float* u2, const float* bq, const float* bk,
              const float* wvec, float* attn, const float* bv, float* cvec) {
    cg::grid_group grid = cg::this_grid();
    __shared__ _Float16 SM[32768];
    const int bid = blockIdx.x;

    // P0: reduce G f16 partials (+ mirror), 320 virtual blocks
    for (int vb = bid; vb < 320; vb += 256)
        reduce_hu_body(gpart, G16, SM, vb);
    VM0(); __threadfence(); grid.sync();

    // P1: U = Wq * G (split-K4 f16 partials)
    gemm_body(wq16, G16, (void*)partH, 1, SM, bid);
    __threadfence(); grid.sync();

    // P2: reduce U partials (512 virtual)
    for (int vb = bid; vb < 512; vb += 256)
        reduce_body(partH, U16, vb);
    VM0(); __threadfence(); grid.sync();

    // P3: scores partials = U * Wk^T (split-K4, fp32)
    gemm_body(U16, wk16, (void*)partF, 0, SM, bid);
    __threadfence(); grid.sync();

    // P4: softmax (+rank-1 +1/32), 4 rows per block
    for (int r = 0; r < 4; ++r)
        softmax_body(partF, u2, bq, bk, wvec, attn, PT, bid * 4 + r, (float*)SM);
    VM0(); __threadfence(); grid.sync();

    // P5: MT partials = attn^T * Wv (via PT, WvT; split-K4 f16)
    gemm_body(PT, wvT16, (void*)partH, 1, SM, bid);
    __threadfence(); grid.sync();

    // P6: reduce MT partials + c = attn^T bv
    for (int vb = bid; vb < 512; vb += 256)
        reduce_body(partH, MT16, vb);
    if (bid < 64) bv_body(attn, bv, cvec, bid);
}

// stage 128 rows x 64 cols : 4 gload_lds16 per wave
#define STG128(SRC, LD, DST, KT) do { \
    const _Float16* _s = (SRC) + (size_t)(KT) * 64; \
    _Float16* _d = (DST) + 8 * w * 64; \
    gload_lds16(_s, _d); \
    gload_lds16(_s + (size_t)32 * (LD), _d + 2048); \
    gload_lds16(_s + (size_t)64 * (LD), _d + 4096); \
    gload_lds16(_s + (size_t)96 * (LD), _d + 6144); \
} while (0)

// ============================== gemm128: fp32-out, col-bias (out-GEMM) ====
__global__ __launch_bounds__(256, 2)
void gemm128(const _Float16* __restrict__ A, const _Float16* __restrict__ B,
             float* __restrict__ C, const float* __restrict__ bias,
             int lda, int ldb, int ldc, int ksub,
             int ntx, int cpx) {
    __shared__ _Float16 SM[32768];
    const int t = threadIdx.x;
    const int l = t & 63;
    const int w = t >> 6;
    const int wm = w >> 1, wn = w & 1;

    const int hb = blockIdx.x;
    const int lg = (hb & 7) * cpx + (hb >> 3);
    const int by = lg / ntx;
    const int bx = lg - by * ntx;
    const size_t m0 = (size_t)by * 128;
    const size_t n0 = (size_t)bx * 128;

    const int colsw = 8 * ((l & 7) ^ (l >> 3));
    const _Float16* srcA = A + (m0 + 8 * w + (l >> 3)) * (size_t)lda + colsw;
    const _Float16* srcB = B + (n0 + 8 * w + (l >> 3)) * (size_t)ldb + colsw;

    const int cx0 = (((l >> 4) << 4)) ^ ((l & 7) << 4);
    const int cx1 = (64 + ((l >> 4) << 4)) ^ ((l & 7) << 4);
    const char* basePA = (const char*)SM + ((wm * 64 + (l & 15)) << 7);
    const char* basePB = (const char*)SM + 32768 + ((wn * 64 + (l & 15)) << 7);

    f32x4 acc[4][4] = {};
    half8 af[4][2], bf[4][2];

    const int nk = ksub >> 6;

    STG128(srcA, lda, SM + 0, 0);        STG128(srcB, ldb, SM + 16384, 0);
    STG128(srcA, lda, SM + 8192, 1);     STG128(srcB, ldb, SM + 24576, 1);

    for (int kt = 0; kt < nk; ++kt) {
        const int p = kt & 1;
        const int ks = kt + 2;
        const bool hs = ks < nk;
        const char* pA = basePA + p * 16384;
        const char* pB = basePB + p * 16384;

        if (kt == nk - 1) VM0(); else VM8();
        BAR();

#pragma unroll
        for (int fm = 0; fm < 4; ++fm) {
            af[fm][0] = *(const half8*)(pA + ((fm * 16) << 7) + cx0);
            af[fm][1] = *(const half8*)(pA + ((fm * 16) << 7) + cx1);
        }
#pragma unroll
        for (int fn = 0; fn < 4; ++fn) {
            bf[fn][0] = *(const half8*)(pB + ((fn * 16) << 7) + cx0);
            bf[fn][1] = *(const half8*)(pB + ((fn * 16) << 7) + cx1);
        }
        LGKM0();
        PRIO1();
#pragma unroll
        for (int fm = 0; fm < 4; ++fm)
#pragma unroll
            for (int fn = 0; fn < 4; ++fn)
                acc[fm][fn] = __builtin_amdgcn_mfma_f32_16x16x32_f16(af[fm][0], bf[fn][0], acc[fm][fn], 0, 0, 0);
        PRIO0();
        BAR();

        if (hs) {
            STG128(srcA, lda, SM + p * 8192, ks);
            STG128(srcB, ldb, SM + 16384 + p * 8192, ks);
        }
        PRIO1();
#pragma unroll
        for (int fm = 0; fm < 4; ++fm)
#pragma unroll
            for (int fn = 0; fn < 4; ++fn)
                acc[fm][fn] = __builtin_amdgcn_mfma_f32_16x16x32_f16(af[fm][1], bf[fn][1], acc[fm][fn], 0, 0, 0);
        PRIO0();
        BAR();
    }

    float* lw = (float*)((char*)SM + w * 16384);
    const int cr = (l >> 4) << 2;
    const int cc = l & 15;
    float bb4[4];
#pragma unroll
    for (int fn = 0; fn < 4; ++fn)
        bb4[fn] = bias[n0 + wn * 64 + fn * 16 + cc];
#pragma unroll
    for (int h = 0; h < 2; ++h) {
#pragma unroll
        for (int mm2 = 0; mm2 < 2; ++mm2) {
            const int mm = h * 2 + mm2;
#pragma unroll
            for (int fn = 0; fn < 4; ++fn) {
                const int lcol = fn * 16 + cc;
                const int lrow = mm2 * 16 + cr;
#pragma unroll
                for (int r = 0; r < 4; ++r)
                    lw[(lrow + r) * 68 + lcol] = acc[mm][fn][r] + bb4[fn];
            }
        }
        LGKM0();
        const size_t grow0 = m0 + (size_t)wm * 64 + h * 32;
#pragma unroll
        for (int i = 0; i < 8; ++i) {
            const int lrow = i * 4 + (l >> 4);
            const int lcol = (l & 15) * 4;
            const f32x4 v = *(const f32x4*)(lw + lrow * 68 + lcol);
            __builtin_nontemporal_store(v,
                (f32x4*)(C + (size_t)(grow0 + lrow) * ldc + n0 + wn * 64 + lcol));
        }
        LGKM0();
    }
}

// ------------------------------------------------------------- prep kernels
template <int WRITE_ROW, int COLSUM>
__global__ __launch_bounds__(256)
void cast_transpose(const float* __restrict__ in, _Float16* __restrict__ outRow,
                    _Float16* __restrict__ outT, float* __restrict__ msum, int ldT) {
    __shared__ _Float16 tile[64][66];
    __shared__ float red[16][16][4];
    const int t = threadIdx.x;
    const int c0 = blockIdx.x * 64;
    const int r0 = blockIdx.y * 64;
    const int cg = t & 15;
    const int rb = t >> 4;
    f32x4 csum = {};
#pragma unroll
    for (int it = 0; it < 4; ++it) {
        const int rr = rb + it * 16;
        f32x4 v = *(const f32x4*)(in + (size_t)(r0 + rr) * 1024 + c0 + cg * 4);
        if (COLSUM) { csum[0] += v[0]; csum[1] += v[1]; csum[2] += v[2]; csum[3] += v[3]; }
        _Float16 h0 = (_Float16)v[0], h1 = (_Float16)v[1];
        _Float16 h2 = (_Float16)v[2], h3 = (_Float16)v[3];
        tile[rr][cg * 4 + 0] = h0; tile[rr][cg * 4 + 1] = h1;
        tile[rr][cg * 4 + 2] = h2; tile[rr][cg * 4 + 3] = h3;
        if (WRITE_ROW) {
            half4 h = {h0, h1, h2, h3};
            *(half4*)(outRow + (size_t)(r0 + rr) * 1024 + c0 + cg * 4) = h;
        }
    }
    if (COLSUM) {
        red[rb][cg][0] = csum[0]; red[rb][cg][1] = csum[1];
        red[rb][cg][2] = csum[2]; red[rb][cg][3] = csum[3];
    }
    __syncthreads();
    if (COLSUM && t < 64) {
        float s = 0.f;
#pragma unroll
        for (int k = 0; k < 16; ++k) s += red[k][t >> 2][t & 3];
        atomicAdd(msum + c0 + t, s);
    }
    const int i = t >> 2, ch = (t & 3) * 16;
    half8 h0v, h1v;
#pragma unroll
    for (int j = 0; j < 8; ++j) h0v[j] = tile[ch + j][i];
#pragma unroll
    for (int j = 0; j < 8; ++j) h1v[j] = tile[ch + 8 + j][i];
    *(half8*)(outT + (size_t)(c0 + i) * ldT + r0 + ch) = h0v;
    *(half8*)(outT + (size_t)(c0 + i) * ldT + r0 + ch + 8) = h1v;
}

__global__ void zero_vec(float* __restrict__ p, int n) {
    int i = blockIdx.x * 256 + threadIdx.x;
    if (i < n) p[i] = 0.f;
}

extern "C" void kernel_launch(void* const* d_in, const int* in_sizes, int n_in,
                              void* d_out, int out_size, void* d_ws, size_t ws_size,
                              hipStream_t stream) {
    const float* x  = (const float*)d_in[0];
    const float* Wq = (const float*)d_in[1];
    const float* bq = (const float*)d_in[2];
    const float* Wk = (const float*)d_in[3];
    const float* bk = (const float*)d_in[4];
    const float* Wv = (const float*)d_in[5];
    const float* bv = (const float*)d_in[6];
    float* out  = (float*)d_out;                   // [S,D] fp32
    float* attn = out + (size_t)S_ * D_;           // [D,D] fp32

    char* ws = (char*)d_ws;
    float*    part  = (float*)ws;                          // 32MB, reused
    _Float16* partH = (_Float16*)ws;                       // f16 partial alias
    _Float16* x16   = (_Float16*)(ws + 33554432);          // [S,D]   33.5MB
    _Float16* xT16  = (_Float16*)(ws + 67108864);          // [D,S]   33.5MB
    _Float16* wq16  = (_Float16*)(ws + 100663296);         // [D,D]   2MB
    _Float16* wk16  = (_Float16*)(ws + 102760448);
    _Float16* wvT16 = (_Float16*)(ws + 104857600);
    _Float16* G16   = (_Float16*)(ws + 106954752);
    _Float16* U16   = (_Float16*)(ws + 109051904);
    _Float16* PT    = (_Float16*)(ws + 111149056);
    _Float16* MT16  = (_Float16*)(ws + 113246208);
    float*    mvec  = (float*)(ws + 115343360);            // m, u2, w, c
    float*    u2    = mvec + 1024;
    float*    wv    = u2 + 1024;
    float*    cvec  = wv + 1024;

    zero_vec<<<16, 256, 0, stream>>>(mvec, 4096);
    cast_transpose<1, 1><<<dim3(16, 256), 256, 0, stream>>>(x, x16, xT16, mvec, S_);
    g_and_prep<<<800, 512, 0, stream>>>(xT16, partH, Wq, Wk, Wv, bq, mvec,
                                        wq16, wk16, wvT16, u2, wv);

    // cooperative mid-chain: reduceG+mirror / U / reduceU / scores /
    // softmax / MT / reduceMT+bv — one launch, grid.sync between phases.
    {
        void* args[] = {
            (void*)&partH, (void*)&G16, (void*)&wq16, (void*)&wk16,
            (void*)&wvT16, (void*)&partH, (void*)&part, (void*)&U16,
            (void*)&MT16, (void*)&PT, (void*)&u2, (void*)&bq, (void*)&bk,
            (void*)&wv, (void*)&attn, (void*)&bv, (void*)&cvec
        };
        hipLaunchCooperativeKernel((void*)midchain, dim3(256), dim3(256),
                                   args, 0, stream);
    }

    // out = x16 * MT^T + cvec  (M=16384, N=1024, K=1024; 1024 blocks, 2/CU)
    gemm128<<<1024, 256, 0, stream>>>(x16, MT16, out, cvec,
                                      1024, 1024, 1024, 1024, 8, 128);
}

// Round 16
// 154.835 us; speedup vs baseline: 3.3578x; 3.3578x over previous
//
#include <hip/hip_runtime.h>
#include <hip/hip_bf16.h>
#include <stdint.h>

// BertAttention (feature-axis attention), algebraically restructured:
//   G = x^T x  [D,D] (SYMMETRIC -> 10/16 tile-pairs);  m = colsum(x)
//   u2 = Wq m + S*bq;  w = Wk m
//   scores = (Wq G Wk^T + u2 bk^T + bq w^T)/sqrt(D); attn = softmax(scores)
//   out = x (Wv^T attn) + 1 (bv^T attn)
// Fusions: G-GEMM + weight-prep co-launched (idle-CU overlap); mirror fused
// into G-reduce; attn_bv fused into MT-GEMM launch. 11 launches total.
// (Round-14 best: 155.0 us. Round-15 cooperative-midchain experiment
// regressed 3.4x -- grid.sync costs ~55us/sync across non-coherent XCDs.)

#define S_ 16384
#define D_ 1024

typedef _Float16 half8 __attribute__((ext_vector_type(8)));
typedef _Float16 half4 __attribute__((ext_vector_type(4)));
typedef float f32x4 __attribute__((ext_vector_type(4)));

__device__ __forceinline__ void gload_lds16(const _Float16* g, _Float16* l) {
    __builtin_amdgcn_global_load_lds(
        (const __attribute__((address_space(1))) void*)g,
        (__attribute__((address_space(3))) void*)l, 16, 0, 0);
}

#define VM8() do { asm volatile("s_waitcnt vmcnt(8)" ::: "memory"); __builtin_amdgcn_sched_barrier(0); } while (0)
#define VM0() do { asm volatile("s_waitcnt vmcnt(0)" ::: "memory"); __builtin_amdgcn_sched_barrier(0); } while (0)
#define BAR() __builtin_amdgcn_s_barrier()
#define LGKM0() do { asm volatile("s_waitcnt lgkmcnt(0)" ::: "memory"); __builtin_amdgcn_sched_barrier(0); } while (0)
#define LGKM8() do { asm volatile("s_waitcnt lgkmcnt(8)" ::: "memory"); __builtin_amdgcn_sched_barrier(0); } while (0)
#define PRIO1() __builtin_amdgcn_s_setprio(1)
#define PRIO0() __builtin_amdgcn_s_setprio(0)

// upper-triangle pair decode (4x4 tiles, by<=bx), pi in [0,10)
#define PAIR10(PI, BY, BX) do { \
    if ((PI) < 4) { BY = 0; BX = (PI); } \
    else if ((PI) < 7) { BY = 1; BX = (PI) - 3; } \
    else if ((PI) < 9) { BY = 2; BX = (PI) - 5; } \
    else { BY = 3; BX = 3; } \
} while (0)

// ========== g_and_prep: blocks [0,160) = G-GEMM (256^2 engine, upper
// triangle, z=16, f16 partials); blocks [160,800) = weight prep (each
// simulates TWO 256-thread prep blocks; both halves provably same path).
#define STAGEA(H, KT, NX) do { \
    const _Float16* _s = srcA + (size_t)((H) * 128) * 16384 + (size_t)(KT) * 64; \
    _Float16* _d = AsS + (NX) * 16384 + ((H) * 128 + 8 * w) * 64; \
    gload_lds16(_s, _d); \
    gload_lds16(_s + (size_t)64 * 16384, _d + 4096); \
} while (0)

#define STAGEB(H, KT, NX) do { \
    const _Float16* _s = srcB + (size_t)((H) * 128) * 16384 + (size_t)(KT) * 64; \
    _Float16* _d = BsS + (NX) * 16384 + ((H) * 128 + 8 * w) * 64; \
    gload_lds16(_s, _d); \
    gload_lds16(_s + (size_t)64 * 16384, _d + 4096); \
} while (0)

#define READA(PA, QA) do { _Pragma("unroll") \
    for (int fm = 0; fm < 4; ++fm) { \
        af[fm][0] = *(const half8*)((PA) + (((QA) * 128 + fm * 16) << 7) + cx0); \
        af[fm][1] = *(const half8*)((PA) + (((QA) * 128 + fm * 16) << 7) + cx1); } \
} while (0)

#define READB(PB, BF, QB) do { _Pragma("unroll") \
    for (int fn = 0; fn < 2; ++fn) { \
        BF[fn][0] = *(const half8*)((PB) + (((QB) * 128 + fn * 16) << 7) + cx0); \
        BF[fn][1] = *(const half8*)((PB) + (((QB) * 128 + fn * 16) << 7) + cx1); } \
} while (0)

#define MFMAB(QA, QB, BF) do { _Pragma("unroll") \
    for (int fm = 0; fm < 4; ++fm) { _Pragma("unroll") \
        for (int fn = 0; fn < 2; ++fn) { \
            f32x4 _c = acc[(QA) * 4 + fm][(QB) * 2 + fn]; \
            _c = __builtin_amdgcn_mfma_f32_16x16x32_f16(af[fm][0], BF[fn][0], _c, 0, 0, 0); \
            _c = __builtin_amdgcn_mfma_f32_16x16x32_f16(af[fm][1], BF[fn][1], _c, 0, 0, 0); \
            acc[(QA) * 4 + fm][(QB) * 2 + fn] = _c; } } \
} while (0)

__global__ __launch_bounds__(512, 2)
void g_and_prep(const _Float16* __restrict__ A, _Float16* __restrict__ C,
                const float* __restrict__ Wq, const float* __restrict__ Wk,
                const float* __restrict__ Wv, const float* __restrict__ bq,
                const float* __restrict__ m,
                _Float16* __restrict__ wq16, _Float16* __restrict__ wk16,
                _Float16* __restrict__ wvT16,
                float* __restrict__ u2, float* __restrict__ wvec) {
    __shared__ _Float16 SM2[65536];   // 128KB
    const int t = threadIdx.x;

    if (blockIdx.x < 160) {
        _Float16* AsS = SM2;
        _Float16* BsS = SM2 + 32768;
        const int l = t & 63;
        const int w = t >> 6;
        const int wm = w >> 2, wn = w & 3;

        const int hb = blockIdx.x;
        const int lg = (hb & 7) * 20 + (hb >> 3);
        const int bz = lg / 10;
        const int pi = lg - bz * 10;
        int by, bx;
        PAIR10(pi, by, bx);
        const size_t m0 = (size_t)by * 256;
        const size_t n0 = (size_t)bx * 256;
        const size_t k0 = (size_t)bz * 1024;
        const long long coff = (long long)bz * 1048576LL;

        const int colsw = 8 * ((l & 7) ^ (l >> 3));
        const _Float16* srcA = A + (m0 + 8 * w + (l >> 3)) * (size_t)16384 + k0 + colsw;
        const _Float16* srcB = A + (n0 + 8 * w + (l >> 3)) * (size_t)16384 + k0 + colsw;

        const int cx0 = (((l >> 4) << 4)) ^ ((l & 7) << 4);
        const int cx1 = (64 + ((l >> 4) << 4)) ^ ((l & 7) << 4);
        const char* basePA = (const char*)AsS + ((wm * 64 + (l & 15)) << 7);
        const char* basePB = (const char*)BsS + ((wn * 32 + (l & 15)) << 7);

        f32x4 acc[8][4] = {};
        half8 af[4][2], bf0[2][2], bf1[2][2];

        const int nk = 16;

        STAGEA(0, 0, 0); STAGEB(0, 0, 0); STAGEB(1, 0, 0); STAGEA(1, 0, 0);
        STAGEA(0, 1, 1); STAGEB(0, 1, 1); STAGEB(1, 1, 1); STAGEA(1, 1, 1);

        for (int kt = 0; kt < nk; ++kt) {
            const int p = kt & 1;
            const int ks = kt + 2;
            const bool hs = ks < nk;
            const char* pA = basePA + p * 32768;
            const char* pB = basePB + p * 32768;

            if (kt == nk - 1) VM0(); else VM8();
            BAR();

            READA(pA, 0); READB(pB, bf0, 0);
            LGKM8();
            BAR(); LGKM0();
            PRIO1(); MFMAB(0, 0, bf0); PRIO0(); BAR();

            READB(pB, bf1, 1);
            if (hs) { STAGEA(0, ks, p); STAGEB(0, ks, p); }
            BAR(); LGKM0();
            PRIO1(); MFMAB(0, 1, bf1); PRIO0(); BAR();

            READA(pA, 1);
            if (hs) STAGEB(1, ks, p);
            BAR(); LGKM0();
            PRIO1(); MFMAB(1, 1, bf1); PRIO0(); BAR();

            if (hs) STAGEA(1, ks, p);
            PRIO1(); MFMAB(1, 0, bf0); PRIO0(); BAR();
        }

        _Float16* eb = SM2;
        const int cr = (l >> 4) << 2;
        const int cc = l & 15;
#pragma unroll
        for (int h = 0; h < 2; ++h) {
            BAR();
#pragma unroll
            for (int mm = 0; mm < 4; ++mm) {
#pragma unroll
                for (int n = 0; n < 4; ++n) {
                    const int lrow0 = wm * 64 + mm * 16 + cr;
                    const int lcol = (n >> 1) * 128 + wn * 32 + (n & 1) * 16 + cc;
#pragma unroll
                    for (int r = 0; r < 4; ++r)
                        eb[(lrow0 + r) * 264 + lcol] = (_Float16)acc[h * 4 + mm][n][r];
                }
            }
            LGKM0();
            BAR();
#pragma unroll
            for (int i = 0; i < 8; ++i) {
                const int lrow = w * 16 + i * 2 + (l >> 5);
                const half8 v = *(const half8*)(eb + lrow * 264 + (l & 31) * 8);
                const size_t row = m0 + (size_t)h * 128 + lrow;
                const size_t col = n0 + (l & 31) * 8;
                __builtin_nontemporal_store(v,
                    (half8*)(C + coff + (long long)row * 1024 + col));
            }
            LGKM0();
        }
        return;
    }

    // prep path (two virtual 256-thread blocks)
    const int h = t >> 8;
    const int vt = t & 255;
    const int vb = (blockIdx.x - 160) * 2 + h;
    _Float16* tileh = SM2 + h * 4224;
    float* wredAll = (float*)(SM2 + 16896);
    const bool isW = vb < 1024;

    if (isW) {
        const bool isQ = vb < 512;
        const int bb = isQ ? vb : vb - 512;
        const float* W = isQ ? Wq : Wk;
        _Float16* o = isQ ? wq16 : wk16;
        const size_t base = (size_t)bb * 2048 + (size_t)vt * 8;
        const f32x4* p = (const f32x4*)(W + base);
        f32x4 x0 = p[0], x1 = p[1];
        half8 hv;
        hv[0] = (_Float16)x0[0]; hv[1] = (_Float16)x0[1];
        hv[2] = (_Float16)x0[2]; hv[3] = (_Float16)x0[3];
        hv[4] = (_Float16)x1[0]; hv[5] = (_Float16)x1[1];
        hv[6] = (_Float16)x1[2]; hv[7] = (_Float16)x1[3];
        ((half8*)o)[bb * 256 + vt] = hv;
        const int col = (vt * 8) & 1023;
        f32x4 m0v = *(const f32x4*)(m + col);
        f32x4 m1v = *(const f32x4*)(m + col + 4);
        float s = x0[0] * m0v[0] + x0[1] * m0v[1] + x0[2] * m0v[2] + x0[3] * m0v[3]
                + x1[0] * m1v[0] + x1[1] * m1v[1] + x1[2] * m1v[2] + x1[3] * m1v[3];
        for (int o2 = 32; o2; o2 >>= 1) s += __shfl_xor(s, o2);
        if ((t & 63) == 0) wredAll[t >> 6] = s;
    } else {
        const int bb = vb - 1024;
        const int c0 = (bb & 15) * 64;
        const int r0 = (bb >> 4) * 64;
        const int cg = vt & 15;
        const int rb = vt >> 4;
#pragma unroll
        for (int it = 0; it < 4; ++it) {
            const int rr = rb + it * 16;
            f32x4 v = *(const f32x4*)(Wv + (size_t)(r0 + rr) * 1024 + c0 + cg * 4);
            tileh[rr * 66 + cg * 4 + 0] = (_Float16)v[0];
            tileh[rr * 66 + cg * 4 + 1] = (_Float16)v[1];
            tileh[rr * 66 + cg * 4 + 2] = (_Float16)v[2];
            tileh[rr * 66 + cg * 4 + 3] = (_Float16)v[3];
        }
    }
    __syncthreads();
    if (isW) {
        if (vt == 0) {
            const bool isQ = vb < 512;
            const int bb = isQ ? vb : vb - 512;
            const int rA = 2 * bb, rB = 2 * bb + 1;
            const float vA = wredAll[h * 4 + 0] + wredAll[h * 4 + 1];
            const float vB = wredAll[h * 4 + 2] + wredAll[h * 4 + 3];
            if (isQ) {
                u2[rA] = vA + 16384.0f * bq[rA];
                u2[rB] = vB + 16384.0f * bq[rB];
            } else {
                wvec[rA] = vA;
                wvec[rB] = vB;
            }
        }
    } else {
        const int bb = vb - 1024;
        const int c0 = (bb & 15) * 64;
        const int r0 = (bb >> 4) * 64;
        const int i = vt >> 2, ch = (vt & 3) * 16;
        half8 h0v, h1v;
#pragma unroll
        for (int j = 0; j < 8; ++j) h0v[j] = tileh[(ch + j) * 66 + i];
#pragma unroll
        for (int j = 0; j < 8; ++j) h1v[j] = tileh[(ch + 8 + j) * 66 + i];
        *(half8*)(wvT16 + (size_t)(c0 + i) * 1024 + r0 + ch) = h0v;
        *(half8*)(wvT16 + (size_t)(c0 + i) * 1024 + r0 + ch + 8) = h1v;
    }
}

// reduce 16 f16 z-slices over upper-triangle tiles -> G16; off-diagonal
// tiles ALSO write the LDS-transposed chunk into the mirrored lower tile.
__global__ __launch_bounds__(256)
void reduce_h_u(const _Float16* __restrict__ part, _Float16* __restrict__ G16) {
    __shared__ _Float16 lt[256][9];
    const int b = blockIdx.x;
    const int ti = b >> 5;
    int by, bx;
    PAIR10(ti, by, bx);
    const int t = threadIdx.x;
    const int e0 = (b & 31) * 2048 + t * 8;
    const size_t row = (size_t)by * 256 + (e0 >> 8);
    const size_t col = (size_t)bx * 256 + (e0 & 255);
    const size_t off = row * 1024 + col;
    float s[8] = {};
    for (int z = 0; z < 16; ++z) {
        half8 v = *(const half8*)(part + (size_t)z * 1048576 + off);
#pragma unroll
        for (int j = 0; j < 8; ++j) s[j] += (float)v[j];
    }
    half8 o;
#pragma unroll
    for (int j = 0; j < 8; ++j) o[j] = (_Float16)s[j];
    *(half8*)(G16 + off) = o;

    const bool offd = (by != bx);
    if (offd) {
        const int cl = (t & 31) * 8;
        const int rl = t >> 5;
#pragma unroll
        for (int j = 0; j < 8; ++j) lt[cl + j][rl] = o[j];
    }
    __syncthreads();
    if (offd) {
        half8 v = *(const half8*)(&lt[t][0]);
        *(half8*)(G16 + ((size_t)(bx * 256 + t)) * 1024 + by * 256 + (b & 31) * 8) = v;
    }
}

// stage 128 rows x 64 cols (one operand K-tile) : 4 gload_lds16 per wave
#define STG128(SRC, LD, DST, KT) do { \
    const _Float16* _s = (SRC) + (size_t)(KT) * 64; \
    _Float16* _d = (DST) + 8 * w * 64; \
    gload_lds16(_s, _d); \
    gload_lds16(_s + (size_t)32 * (LD), _d + 2048); \
    gload_lds16(_s + (size_t)64 * (LD), _d + 4096); \
    gload_lds16(_s + (size_t)96 * (LD), _d + 6144); \
} while (0)

// ============================== gemm128: fp32-out, col-bias (out-GEMM) ====
__global__ __launch_bounds__(256, 2)
void gemm128(const _Float16* __restrict__ A, const _Float16* __restrict__ B,
             float* __restrict__ C, const float* __restrict__ bias,
             int lda, int ldb, int ldc, int ksub,
             int ntx, int cpx) {
    __shared__ _Float16 SM[32768];
    const int t = threadIdx.x;
    const int l = t & 63;
    const int w = t >> 6;
    const int wm = w >> 1, wn = w & 1;

    const int hb = blockIdx.x;
    const int lg = (hb & 7) * cpx + (hb >> 3);
    const int by = lg / ntx;
    const int bx = lg - by * ntx;
    const size_t m0 = (size_t)by * 128;
    const size_t n0 = (size_t)bx * 128;

    const int colsw = 8 * ((l & 7) ^ (l >> 3));
    const _Float16* srcA = A + (m0 + 8 * w + (l >> 3)) * (size_t)lda + colsw;
    const _Float16* srcB = B + (n0 + 8 * w + (l >> 3)) * (size_t)ldb + colsw;

    const int cx0 = (((l >> 4) << 4)) ^ ((l & 7) << 4);
    const int cx1 = (64 + ((l >> 4) << 4)) ^ ((l & 7) << 4);
    const char* basePA = (const char*)SM + ((wm * 64 + (l & 15)) << 7);
    const char* basePB = (const char*)SM + 32768 + ((wn * 64 + (l & 15)) << 7);

    f32x4 acc[4][4] = {};
    half8 af[4][2], bf[4][2];

    const int nk = ksub >> 6;

    STG128(srcA, lda, SM + 0, 0);        STG128(srcB, ldb, SM + 16384, 0);
    STG128(srcA, lda, SM + 8192, 1);     STG128(srcB, ldb, SM + 24576, 1);

    for (int kt = 0; kt < nk; ++kt) {
        const int p = kt & 1;
        const int ks = kt + 2;
        const bool hs = ks < nk;
        const char* pA = basePA + p * 16384;
        const char* pB = basePB + p * 16384;

        if (kt == nk - 1) VM0(); else VM8();
        BAR();

#pragma unroll
        for (int fm = 0; fm < 4; ++fm) {
            af[fm][0] = *(const half8*)(pA + ((fm * 16) << 7) + cx0);
            af[fm][1] = *(const half8*)(pA + ((fm * 16) << 7) + cx1);
        }
#pragma unroll
        for (int fn = 0; fn < 4; ++fn) {
            bf[fn][0] = *(const half8*)(pB + ((fn * 16) << 7) + cx0);
            bf[fn][1] = *(const half8*)(pB + ((fn * 16) << 7) + cx1);
        }
        LGKM0();
        PRIO1();
#pragma unroll
        for (int fm = 0; fm < 4; ++fm)
#pragma unroll
            for (int fn = 0; fn < 4; ++fn)
                acc[fm][fn] = __builtin_amdgcn_mfma_f32_16x16x32_f16(af[fm][0], bf[fn][0], acc[fm][fn], 0, 0, 0);
        PRIO0();
        BAR();

        if (hs) {
            STG128(srcA, lda, SM + p * 8192, ks);
            STG128(srcB, ldb, SM + 16384 + p * 8192, ks);
        }
        PRIO1();
#pragma unroll
        for (int fm = 0; fm < 4; ++fm)
#pragma unroll
            for (int fn = 0; fn < 4; ++fn)
                acc[fm][fn] = __builtin_amdgcn_mfma_f32_16x16x32_f16(af[fm][1], bf[fn][1], acc[fm][fn], 0, 0, 0);
        PRIO0();
        BAR();
    }

    float* lw = (float*)((char*)SM + w * 16384);
    const int cr = (l >> 4) << 2;
    const int cc = l & 15;
    float bb4[4];
#pragma unroll
    for (int fn = 0; fn < 4; ++fn)
        bb4[fn] = bias[n0 + wn * 64 + fn * 16 + cc];
#pragma unroll
    for (int h = 0; h < 2; ++h) {
#pragma unroll
        for (int mm2 = 0; mm2 < 2; ++mm2) {
            const int mm = h * 2 + mm2;
#pragma unroll
            for (int fn = 0; fn < 4; ++fn) {
                const int lcol = fn * 16 + cc;
                const int lrow = mm2 * 16 + cr;
#pragma unroll
                for (int r = 0; r < 4; ++r)
                    lw[(lrow + r) * 68 + lcol] = acc[mm][fn][r] + bb4[fn];
            }
        }
        LGKM0();
        const size_t grow0 = m0 + (size_t)wm * 64 + h * 32;
#pragma unroll
        for (int i = 0; i < 8; ++i) {
            const int lrow = i * 4 + (l >> 4);
            const int lcol = (l & 15) * 4;
            const f32x4 v = *(const f32x4*)(lw + lrow * 68 + lcol);
            __builtin_nontemporal_store(v,
                (f32x4*)(C + (size_t)(grow0 + lrow) * ldc + n0 + wn * 64 + lcol));
        }
        LGKM0();
    }
}

// ======== gemm_s128<F16OUT>: split-K engine (U / scores) ========
template <int F16OUT>
__global__ __launch_bounds__(256, 2)
void gemm_s128(const _Float16* __restrict__ A, const _Float16* __restrict__ B,
               void* __restrict__ C, int lda, int ldb, int ldc, int ksub,
               long long mn) {
    __shared__ _Float16 SM[32768];
    const int t = threadIdx.x;
    const int l = t & 63;
    const int w = t >> 6;
    const int wm = w >> 1, wn = w & 1;

    const size_t m0 = (size_t)blockIdx.y * 128;
    const size_t n0 = (size_t)blockIdx.x * 128;
    const size_t k0 = (size_t)blockIdx.z * (size_t)ksub;
    const long long coff = (long long)blockIdx.z * mn;

    const int colsw = 8 * ((l & 7) ^ (l >> 3));
    const _Float16* srcA = A + (m0 + 8 * w + (l >> 3)) * (size_t)lda + k0 + colsw;
    const _Float16* srcB = B + (n0 + 8 * w + (l >> 3)) * (size_t)ldb + k0 + colsw;

    const int cx0 = (((l >> 4) << 4)) ^ ((l & 7) << 4);
    const int cx1 = (64 + ((l >> 4) << 4)) ^ ((l & 7) << 4);
    const char* basePA = (const char*)SM + ((wm * 64 + (l & 15)) << 7);
    const char* basePB = (const char*)SM + 32768 + ((wn * 64 + (l & 15)) << 7);

    f32x4 acc[4][4] = {};
    half8 af[4][2], bf[4][2];

    const int nk = ksub >> 6;

    STG128(srcA, lda, SM + 0, 0);        STG128(srcB, ldb, SM + 16384, 0);
    STG128(srcA, lda, SM + 8192, 1);     STG128(srcB, ldb, SM + 24576, 1);

    for (int kt = 0; kt < nk; ++kt) {
        const int p = kt & 1;
        const int ks = kt + 2;
        const bool hs = ks < nk;
        const char* pA = basePA + p * 16384;
        const char* pB = basePB + p * 16384;

        if (kt == nk - 1) VM0(); else VM8();
        BAR();

#pragma unroll
        for (int fm = 0; fm < 4; ++fm) {
            af[fm][0] = *(const half8*)(pA + ((fm * 16) << 7) + cx0);
            af[fm][1] = *(const half8*)(pA + ((fm * 16) << 7) + cx1);
        }
#pragma unroll
        for (int fn = 0; fn < 4; ++fn) {
            bf[fn][0] = *(const half8*)(pB + ((fn * 16) << 7) + cx0);
            bf[fn][1] = *(const half8*)(pB + ((fn * 16) << 7) + cx1);
        }
        LGKM0();
        PRIO1();
#pragma unroll
        for (int fm = 0; fm < 4; ++fm)
#pragma unroll
            for (int fn = 0; fn < 4; ++fn)
                acc[fm][fn] = __builtin_amdgcn_mfma_f32_16x16x32_f16(af[fm][0], bf[fn][0], acc[fm][fn], 0, 0, 0);
        PRIO0();
        BAR();

        if (hs) {
            STG128(srcA, lda, SM + p * 8192, ks);
            STG128(srcB, ldb, SM + 16384 + p * 8192, ks);
        }
        PRIO1();
#pragma unroll
        for (int fm = 0; fm < 4; ++fm)
#pragma unroll
            for (int fn = 0; fn < 4; ++fn)
                acc[fm][fn] = __builtin_amdgcn_mfma_f32_16x16x32_f16(af[fm][1], bf[fn][1], acc[fm][fn], 0, 0, 0);
        PRIO0();
        BAR();
    }

    const int cr = (l >> 4) << 2;
    const int cc = l & 15;

    if (F16OUT) {
        _Float16* eb = SM;
#pragma unroll
        for (int fm = 0; fm < 4; ++fm) {
#pragma unroll
            for (int fn = 0; fn < 4; ++fn) {
                const int lrow0 = wm * 64 + fm * 16 + cr;
                const int lcol = wn * 64 + fn * 16 + cc;
#pragma unroll
                for (int r = 0; r < 4; ++r)
                    eb[(lrow0 + r) * 132 + lcol] = (_Float16)acc[fm][fn][r];
            }
        }
        LGKM0();
        BAR();
        _Float16* Ch = (_Float16*)C;
#pragma unroll
        for (int i = 0; i < 8; ++i) {
            const int row = i * 16 + (t >> 4);
            const int colh = (t & 15) * 8;
            const half8 v = *(const half8*)(eb + row * 132 + colh);
            *(half8*)(Ch + coff + (long long)(m0 + row) * ldc + n0 + colh) = v;
        }
    } else {
        float* lw = (float*)((char*)SM + w * 16384);
        float* Cf = (float*)C;
#pragma unroll
        for (int h = 0; h < 2; ++h) {
#pragma unroll
            for (int mm2 = 0; mm2 < 2; ++mm2) {
                const int mm = h * 2 + mm2;
#pragma unroll
                for (int fn = 0; fn < 4; ++fn) {
                    const int lcol = fn * 16 + cc;
                    const int lrow = mm2 * 16 + cr;
#pragma unroll
                    for (int r = 0; r < 4; ++r)
                        lw[(lrow + r) * 68 + lcol] = acc[mm][fn][r];
                }
            }
            LGKM0();
            const size_t grow0 = m0 + (size_t)wm * 64 + h * 32;
#pragma unroll
            for (int i = 0; i < 8; ++i) {
                const int lrow = i * 4 + (l >> 4);
                const int lcol = (l & 15) * 4;
                const f32x4 v = *(const f32x4*)(lw + lrow * 68 + lcol);
                *(f32x4*)(Cf + coff + (long long)(grow0 + lrow) * ldc + n0 + wn * 64 + lcol) = v;
            }
            LGKM0();
        }
    }
}

// ======== gemm_mt_bv: blocks [0,256) = MT GEMM (gemm_s128<1> body, 1D
// decode); blocks [256,320) = attn_bv (c = attn^T bv). ========
__global__ __launch_bounds__(256, 2)
void gemm_mt_bv(const _Float16* __restrict__ A, const _Float16* __restrict__ B,
                _Float16* __restrict__ Cp,
                const float* __restrict__ attn, const float* __restrict__ bv,
                float* __restrict__ cvec) {
    const int idx = blockIdx.x;
    if (idx >= 256) {
        const int bb = idx - 256;
        const int j = (bb & 3) * 256 + threadIdx.x;
        const int a0 = (bb >> 2) * 64;
        float s = 0.f;
#pragma unroll 4
        for (int k = 0; k < 64; ++k) {
            const int a = a0 + k;
            s += attn[(size_t)a * 1024 + j] * bv[a];
        }
        atomicAdd(cvec + j, s);
        return;
    }

    __shared__ _Float16 SM[32768];
    const int t = threadIdx.x;
    const int l = t & 63;
    const int w = t >> 6;
    const int wm = w >> 1, wn = w & 1;

    const int bx = idx & 7, by = (idx >> 3) & 7, bz = idx >> 6;
    const size_t m0 = (size_t)by * 128;
    const size_t n0 = (size_t)bx * 128;
    const size_t k0 = (size_t)bz * 256;
    const long long coff = (long long)bz * 1048576LL;

    const int colsw = 8 * ((l & 7) ^ (l >> 3));
    const _Float16* srcA = A + (m0 + 8 * w + (l >> 3)) * (size_t)1024 + k0 + colsw;
    const _Float16* srcB = B + (n0 + 8 * w + (l >> 3)) * (size_t)1024 + k0 + colsw;

    const int cx0 = (((l >> 4) << 4)) ^ ((l & 7) << 4);
    const int cx1 = (64 + ((l >> 4) << 4)) ^ ((l & 7) << 4);
    const char* basePA = (const char*)SM + ((wm * 64 + (l & 15)) << 7);
    const char* basePB = (const char*)SM + 32768 + ((wn * 64 + (l & 15)) << 7);

    f32x4 acc[4][4] = {};
    half8 af[4][2], bf[4][2];

    const int nk = 4;

    STG128(srcA, 1024, SM + 0, 0);        STG128(srcB, 1024, SM + 16384, 0);
    STG128(srcA, 1024, SM + 8192, 1);     STG128(srcB, 1024, SM + 24576, 1);

    for (int kt = 0; kt < nk; ++kt) {
        const int p = kt & 1;
        const int ks = kt + 2;
        const bool hs = ks < nk;
        const char* pA = basePA + p * 16384;
        const char* pB = basePB + p * 16384;

        if (kt == nk - 1) VM0(); else VM8();
        BAR();

#pragma unroll
        for (int fm = 0; fm < 4; ++fm) {
            af[fm][0] = *(const half8*)(pA + ((fm * 16) << 7) + cx0);
            af[fm][1] = *(const half8*)(pA + ((fm * 16) << 7) + cx1);
        }
#pragma unroll
        for (int fn = 0; fn < 4; ++fn) {
            bf[fn][0] = *(const half8*)(pB + ((fn * 16) << 7) + cx0);
            bf[fn][1] = *(const half8*)(pB + ((fn * 16) << 7) + cx1);
        }
        LGKM0();
        PRIO1();
#pragma unroll
        for (int fm = 0; fm < 4; ++fm)
#pragma unroll
            for (int fn = 0; fn < 4; ++fn)
                acc[fm][fn] = __builtin_amdgcn_mfma_f32_16x16x32_f16(af[fm][0], bf[fn][0], acc[fm][fn], 0, 0, 0);
        PRIO0();
        BAR();

        if (hs) {
            STG128(srcA, 1024, SM + p * 8192, ks);
            STG128(srcB, 1024, SM + 16384 + p * 8192, ks);
        }
        PRIO1();
#pragma unroll
        for (int fm = 0; fm < 4; ++fm)
#pragma unroll
            for (int fn = 0; fn < 4; ++fn)
                acc[fm][fn] = __builtin_amdgcn_mfma_f32_16x16x32_f16(af[fm][1], bf[fn][1], acc[fm][fn], 0, 0, 0);
        PRIO0();
        BAR();
    }

    const int cr = (l >> 4) << 2;
    const int cc = l & 15;
    _Float16* eb = SM;
#pragma unroll
    for (int fm = 0; fm < 4; ++fm) {
#pragma unroll
        for (int fn = 0; fn < 4; ++fn) {
            const int lrow0 = wm * 64 + fm * 16 + cr;
            const int lcol = wn * 64 + fn * 16 + cc;
#pragma unroll
            for (int r = 0; r < 4; ++r)
                eb[(lrow0 + r) * 132 + lcol] = (_Float16)acc[fm][fn][r];
        }
    }
    LGKM0();
    BAR();
#pragma unroll
    for (int i = 0; i < 8; ++i) {
        const int row = i * 16 + (t >> 4);
        const int colh = (t & 15) * 8;
        const half8 v = *(const half8*)(eb + row * 132 + colh);
        *(half8*)(Cp + coff + (long long)(m0 + row) * 1024 + n0 + colh) = v;
    }
}

// ------------------------------------------------------------- prep kernels
template <int WRITE_ROW, int COLSUM>
__global__ __launch_bounds__(256)
void cast_transpose(const float* __restrict__ in, _Float16* __restrict__ outRow,
                    _Float16* __restrict__ outT, float* __restrict__ msum, int ldT) {
    __shared__ _Float16 tile[64][66];
    __shared__ float red[16][16][4];
    const int t = threadIdx.x;
    const int c0 = blockIdx.x * 64;
    const int r0 = blockIdx.y * 64;
    const int cg = t & 15;
    const int rb = t >> 4;
    f32x4 csum = {};
#pragma unroll
    for (int it = 0; it < 4; ++it) {
        const int rr = rb + it * 16;
        f32x4 v = *(const f32x4*)(in + (size_t)(r0 + rr) * 1024 + c0 + cg * 4);
        if (COLSUM) { csum[0] += v[0]; csum[1] += v[1]; csum[2] += v[2]; csum[3] += v[3]; }
        _Float16 h0 = (_Float16)v[0], h1 = (_Float16)v[1];
        _Float16 h2 = (_Float16)v[2], h3 = (_Float16)v[3];
        tile[rr][cg * 4 + 0] = h0; tile[rr][cg * 4 + 1] = h1;
        tile[rr][cg * 4 + 2] = h2; tile[rr][cg * 4 + 3] = h3;
        if (WRITE_ROW) {
            half4 h = {h0, h1, h2, h3};
            *(half4*)(outRow + (size_t)(r0 + rr) * 1024 + c0 + cg * 4) = h;
        }
    }
    if (COLSUM) {
        red[rb][cg][0] = csum[0]; red[rb][cg][1] = csum[1];
        red[rb][cg][2] = csum[2]; red[rb][cg][3] = csum[3];
    }
    __syncthreads();
    if (COLSUM && t < 64) {
        float s = 0.f;
#pragma unroll
        for (int k = 0; k < 16; ++k) s += red[k][t >> 2][t & 3];
        atomicAdd(msum + c0 + t, s);
    }
    const int i = t >> 2, ch = (t & 3) * 16;
    half8 h0v, h1v;
#pragma unroll
    for (int j = 0; j < 8; ++j) h0v[j] = tile[ch + j][i];
#pragma unroll
    for (int j = 0; j < 8; ++j) h1v[j] = tile[ch + 8 + j][i];
    *(half8*)(outT + (size_t)(c0 + i) * ldT + r0 + ch) = h0v;
    *(half8*)(outT + (size_t)(c0 + i) * ldT + r0 + ch + 8) = h1v;
}

__global__ void zero_vec(float* __restrict__ p, int n) {
    int i = blockIdx.x * 256 + threadIdx.x;
    if (i < n) p[i] = 0.f;
}

// reduce nz f16 split-K slices (stride 1M elems) -> f16, fp32 accumulate
__global__ __launch_bounds__(256)
void reduce_h(const _Float16* __restrict__ part, _Float16* __restrict__ outh,
              int nz) {
    const size_t off = ((size_t)blockIdx.x * 256 + threadIdx.x) * 8;
    float s[8] = {};
    for (int z = 0; z < nz; ++z) {
        half8 v = *(const half8*)(part + (size_t)z * 1048576 + off);
#pragma unroll
        for (int j = 0; j < 8; ++j) s[j] += (float)v[j];
    }
    half8 o;
#pragma unroll
    for (int j = 0; j < 8; ++j) o[j] = (_Float16)s[j];
    *(half8*)(outh + off) = o;
}

// reduce 4 split-K fp32 slices + rank-1 terms + 1/32 scale + row-softmax
__global__ __launch_bounds__(256)
void softmax_rows(const float* __restrict__ part, const float* __restrict__ u2,
                  const float* __restrict__ bq, const float* __restrict__ bk,
                  const float* __restrict__ w,
                  float* __restrict__ P, _Float16* __restrict__ PT) {
    const int a = blockIdx.x;
    const int t = threadIdx.x;
    __shared__ float red[8];
    const size_t off = (size_t)a * 1024 + t * 4;
    f32x4 s = {};
#pragma unroll
    for (int z = 0; z < 4; ++z) {
        f32x4 v = *(const f32x4*)(part + (size_t)z * 1048576 + off);
        s[0] += v[0]; s[1] += v[1]; s[2] += v[2]; s[3] += v[3];
    }
    const float ru = u2[a], rb = bq[a];
    f32x4 bk4 = *(const f32x4*)(bk + t * 4);
    f32x4 w4 = *(const f32x4*)(w + t * 4);
#pragma unroll
    for (int j = 0; j < 4; ++j) s[j] = (s[j] + ru * bk4[j] + rb * w4[j]) * 0.03125f;

    float m = fmaxf(fmaxf(s[0], s[1]), fmaxf(s[2], s[3]));
    for (int o = 32; o; o >>= 1) m = fmaxf(m, __shfl_xor(m, o));
    if ((t & 63) == 0) red[t >> 6] = m;
    __syncthreads();
    m = fmaxf(fmaxf(red[0], red[1]), fmaxf(red[2], red[3]));

    float e0 = expf(s[0] - m), e1 = expf(s[1] - m);
    float e2 = expf(s[2] - m), e3 = expf(s[3] - m);
    float sum = e0 + e1 + e2 + e3;
    for (int o = 32; o; o >>= 1) sum += __shfl_xor(sum, o);
    if ((t & 63) == 0) red[4 + (t >> 6)] = sum;
    __syncthreads();
    sum = red[4] + red[5] + red[6] + red[7];
    const float inv = 1.0f / sum;

    f32x4 o4 = {e0 * inv, e1 * inv, e2 * inv, e3 * inv};
    *(f32x4*)(P + off) = o4;
    const int b = t * 4;
    PT[(size_t)(b + 0) * 1024 + a] = (_Float16)o4[0];
    PT[(size_t)(b + 1) * 1024 + a] = (_Float16)o4[1];
    PT[(size_t)(b + 2) * 1024 + a] = (_Float16)o4[2];
    PT[(size_t)(b + 3) * 1024 + a] = (_Float16)o4[3];
}

extern "C" void kernel_launch(void* const* d_in, const int* in_sizes, int n_in,
                              void* d_out, int out_size, void* d_ws, size_t ws_size,
                              hipStream_t stream) {
    const float* x  = (const float*)d_in[0];
    const float* Wq = (const float*)d_in[1];
    const float* bq = (const float*)d_in[2];
    const float* Wk = (const float*)d_in[3];
    const float* bk = (const float*)d_in[4];
    const float* Wv = (const float*)d_in[5];
    const float* bv = (const float*)d_in[6];
    float* out  = (float*)d_out;                   // [S,D] fp32
    float* attn = out + (size_t)S_ * D_;           // [D,D] fp32

    char* ws = (char*)d_ws;
    float*    part  = (float*)ws;                          // 32MB, reused
    _Float16* partH = (_Float16*)ws;                       // f16 partial alias
    _Float16* x16   = (_Float16*)(ws + 33554432);          // [S,D]   33.5MB
    _Float16* xT16  = (_Float16*)(ws + 67108864);          // [D,S]   33.5MB
    _Float16* wq16  = (_Float16*)(ws + 100663296);         // [D,D]   2MB
    _Float16* wk16  = (_Float16*)(ws + 102760448);
    _Float16* wvT16 = (_Float16*)(ws + 104857600);
    _Float16* G16   = (_Float16*)(ws + 106954752);
    _Float16* U16   = (_Float16*)(ws + 109051904);
    _Float16* PT    = (_Float16*)(ws + 111149056);
    _Float16* MT16  = (_Float16*)(ws + 113246208);
    float*    mvec  = (float*)(ws + 115343360);            // m, u2, w, c
    float*    u2    = mvec + 1024;
    float*    wv    = u2 + 1024;
    float*    cvec  = wv + 1024;

    zero_vec<<<16, 256, 0, stream>>>(mvec, 4096);
    cast_transpose<1, 1><<<dim3(16, 256), 256, 0, stream>>>(x, x16, xT16, mvec, S_);

    // G (blocks 0-159, symmetric tile-pairs, z=16, f16 partials) + weight
    // prep (blocks 160-799) in one launch: prep fills the CUs G leaves idle.
    g_and_prep<<<800, 512, 0, stream>>>(xT16, partH, Wq, Wk, Wv, bq, mvec,
                                        wq16, wk16, wvT16, u2, wv);
    reduce_h_u<<<320, 256, 0, stream>>>(partH, G16);   // + fused mirror
    // U = Wq * G  (split-K4, f16 partials; G symmetric -> A.B^T form)
    gemm_s128<1><<<dim3(8, 8, 4), 256, 0, stream>>>(wq16, G16, (void*)partH,
                                                    1024, 1024, 1024, 256, 1048576);
    reduce_h<<<512, 256, 0, stream>>>(partH, U16, 4);
    // scores partials = U * Wk^T (split-K4 fp32; rank-1 + scale in softmax)
    gemm_s128<0><<<dim3(8, 8, 4), 256, 0, stream>>>(U16, wk16, (void*)part,
                                                    1024, 1024, 1024, 256, 1048576);
    softmax_rows<<<1024, 256, 0, stream>>>(part, u2, bq, bk, wv, attn, PT);
    // MT = attn^T Wv (blocks 0-255) + c = attn^T bv (blocks 256-319)
    gemm_mt_bv<<<320, 256, 0, stream>>>(PT, wvT16, partH, attn, bv, cvec);
    reduce_h<<<512, 256, 0, stream>>>(partH, MT16, 4);
    // out = x16 * MT^T + cvec  (M=16384, N=1024, K=1024; 1024 blocks, 2/CU)
    gemm128<<<1024, 256, 0, stream>>>(x16, MT16, out, cvec,
                                      1024, 1024, 1024, 1024, 8, 128);
}